// Round 6
// baseline (131.805 us; speedup 1.0000x reference)
//
#include <hip/hip_runtime.h>

#define NROW 4096
#define CH   256
#define SEGSLOT 40      // per-1024-col-segment nnz cap (mean ~10.3, +9.5 sigma)
#define LDSNNZ  160     // per-row cap for consumers (4*SEGSLOT)

typedef short  short8  __attribute__((ext_vector_type(8)));
typedef unsigned short ushort8 __attribute__((ext_vector_type(8)));
typedef float  f32x4   __attribute__((ext_vector_type(4)));

__device__ inline unsigned short f2bf(float f) {
  unsigned u = __float_as_uint(f);
  return (unsigned short)((u + 0x7fffu + ((u >> 16) & 1u)) >> 16);
}
__device__ inline float bf2f(unsigned short h) {
  return __uint_as_float((unsigned)h << 16);
}
// popc(m & lanes_below_me) + base
__device__ inline int mbcnt64(unsigned long long m, int base) {
  int t = __builtin_amdgcn_mbcnt_lo((unsigned)m, (unsigned)base);
  return __builtin_amdgcn_mbcnt_hi((unsigned)(m >> 32), t);
}

// ---------------------------------------------------------------------------
// Segmented CSR build. Persistent waves, no block barriers. Unit u encodes
// (mat = u>>14, row = (u>>2)&4095, seg = u&3); u is also the linear
// (mat,row,seg) output index. Each wave: double-buffered 4x float4 prefetch,
// ballot-compaction into a per-wave LDS slice (lgkm domain keeps vmcnt clean),
// then ONE coalesced 320B store + cnt store per unit.
__global__ __launch_bounds__(256) void seg_csr(
    const float* __restrict__ L0, const float* __restrict__ L1,
    const float* __restrict__ L2, int2* __restrict__ segout,
    int* __restrict__ segcnt) {
  __shared__ int2 sbuf[4][SEGSLOT];
  const int wi = threadIdx.x >> 6, lane = threadIdx.x & 63;
  const int NW = 8192;                       // total waves
  int u = blockIdx.x * 4 + wi;

  auto addr = [&](int uu) -> const float4* {
    int mat = uu >> 14;
    const float* Lm = (mat == 0) ? L0 : (mat == 1) ? L1 : L2;
    return (const float4*)(Lm + ((size_t)((uu >> 2) & 4095) << 12) + ((uu & 3) << 10));
  };

  float4 c0, c1, c2, c3;
  { const float4* p = addr(u); c0 = p[lane]; c1 = p[64 + lane]; c2 = p[128 + lane]; c3 = p[192 + lane]; }

#pragma unroll 1
  for (int it = 0; it < 6; ++it) {
    float4 x0, x1, x2, x3;
    if (it < 5) {
      const float4* p = addr(u + NW);
      x0 = p[lane]; x1 = p[64 + lane]; x2 = p[128 + lane]; x3 = p[192 + lane];
    }
    __builtin_amdgcn_sched_barrier(0);       // prefetch issued before compute

    int base = 0;
    int colbase = (u & 3) * 1024 + lane * 4;
#define PROCQ(q, cb) {                                                          \
    bool a0 = q.x != 0.f, a1 = q.y != 0.f, a2 = q.z != 0.f, a3 = q.w != 0.f;    \
    unsigned long long b0 = __ballot(a0), b1 = __ballot(a1);                    \
    unsigned long long b2 = __ballot(a2), b3 = __ballot(a3);                    \
    int off = mbcnt64(b3, mbcnt64(b2, mbcnt64(b1, mbcnt64(b0, base))));         \
    if (a0) { if (off < SEGSLOT) sbuf[wi][off] = make_int2((cb),     __float_as_int(q.x)); ++off; } \
    if (a1) { if (off < SEGSLOT) sbuf[wi][off] = make_int2((cb) + 1, __float_as_int(q.y)); ++off; } \
    if (a2) { if (off < SEGSLOT) sbuf[wi][off] = make_int2((cb) + 2, __float_as_int(q.z)); ++off; } \
    if (a3) { if (off < SEGSLOT) sbuf[wi][off] = make_int2((cb) + 3, __float_as_int(q.w)); ++off; } \
    base += __popcll(b0) + __popcll(b1) + __popcll(b2) + __popcll(b3); }
    PROCQ(c0, colbase)
    PROCQ(c1, colbase + 256)
    PROCQ(c2, colbase + 512)
    PROCQ(c3, colbase + 768)
#undef PROCQ

    int2 e;
    if (lane < SEGSLOT) e = sbuf[wi][lane];
    int2* outp = segout + (size_t)u * SEGSLOT;
    if (lane < SEGSLOT) outp[lane] = e;      // one coalesced 320B store
    if (lane == 0) segcnt[u] = base < SEGSLOT ? base : SEGSLOT;

    c0 = x0; c1 = x1; c2 = x2; c3 = x3;
    u += NW;
  }
}

// ---------------------------------------------------------------------------
// Fold attention vector into linear weights (q = branch*2 + (0:src,1:dst)).
__global__ void fold_att(const float* __restrict__ Wi, const float* __restrict__ bi,
                         const float* __restrict__ ai,
                         const float* __restrict__ Ws, const float* __restrict__ bs,
                         const float* __restrict__ as_,
                         float* __restrict__ wfold, float* __restrict__ bfold) {
  int b  = blockIdx.x >> 1;
  int sd = blockIdx.x & 1;
  const float* Ww  = b ? Ws : Wi;
  const float* Wb  = b ? bs : bi;
  const float* att = (b ? as_ : ai) + sd * 512;
  int c = threadIdx.x;
  float acc = 0.f;
  for (int k = 0; k < 512; ++k) acc += att[k] * Ww[k * 256 + c];
  wfold[blockIdx.x * 256 + c] = acc;
  __shared__ float sb[256];
  sb[c] = att[c] * Wb[c] + att[c + 256] * Wb[c + 256];
  __syncthreads();
  for (int s2 = 128; s2 > 0; s2 >>= 1) { if (c < s2) sb[c] += sb[c + s2]; __syncthreads(); }
  if (c == 0) bfold[blockIdx.x] = sb[0];
}

// ---------------------------------------------------------------------------
// sdv[q][n] = x[n,:] . wfold[q] + bfold[q]
__global__ void src_dst(const float* __restrict__ x, const float* __restrict__ wfold,
                        const float* __restrict__ bfold, float* __restrict__ sdv) {
  int q    = blockIdx.y;
  int row  = blockIdx.x * 4 + (threadIdx.x >> 6);
  int lane = threadIdx.x & 63;
  const float4* xr = (const float4*)(x + (size_t)row * CH);
  const float4* wr = (const float4*)(wfold + q * CH);
  float4 a = xr[lane];
  float4 b = wr[lane];
  float s = a.x * b.x + a.y * b.y + a.z * b.z + a.w * b.w;
  for (int o = 32; o; o >>= 1) s += __shfl_xor(s, o);
  if (lane == 0) sdv[q * NROW + row] = s + bfold[q];
}

// ---------------------------------------------------------------------------
// One dispatch converting x, Wirr_w, Wsol_w, Whar_w to bf16 (4 f32/thread).
__global__ void cvt_all(const float* __restrict__ x, const float* __restrict__ Wi,
                        const float* __restrict__ Ws, const float* __restrict__ Wh,
                        unsigned short* __restrict__ xbf, unsigned short* __restrict__ Bbf) {
  int i = blockIdx.x * 256 + threadIdx.x;       // float4 index
  const float* src; unsigned short* dst; int o;
  if (i < 262144)        { src = x;  dst = xbf;          o = i; }
  else if (i < 294912)   { src = Wi; dst = Bbf;          o = i - 262144; }
  else if (i < 327680)   { src = Ws; dst = Bbf + 131072; o = i - 294912; }
  else                   { src = Wh; dst = Bbf + 262144; o = i - 327680; }
  float4 v = ((const float4*)src)[o];
  ushort4 u;
  u.x = f2bf(v.x); u.y = f2bf(v.y); u.z = f2bf(v.z); u.w = f2bf(v.w);
  ((ushort4*)dst)[o] = u;
}

// ---------------------------------------------------------------------------
// Y[4096][1280] (bf16) = A[4096][256](bf16) @ Bt[1280][256](bf16)^T
// 64x64 tile, 4 waves, full-K (=256) staged in LDS with XOR swizzle.
__global__ __launch_bounds__(256, 2) void gemm_mfma(const unsigned short* __restrict__ A,
                                                    const unsigned short* __restrict__ Bt,
                                                    unsigned short* __restrict__ Y) {
  __shared__ unsigned short sA[64 * 256];
  __shared__ unsigned short sB[64 * 256];
  const int m0 = blockIdx.x * 64, n0 = blockIdx.y * 64;
  const int tid = threadIdx.x, wid = tid >> 6, lane = tid & 63;

  for (int c = 0; c < 8; ++c) {
    int chunk = c * 256 + tid;
    int r  = chunk >> 5;
    int cb = (chunk & 31) * 16;
    int cbs = cb ^ ((r & 7) << 4);
    ushort8 va = *(const ushort8*)((const char*)(A  + (size_t)(m0 + r) * 256) + cb);
    *(ushort8*)((char*)sA + r * 512 + cbs) = va;
    ushort8 vb = *(const ushort8*)((const char*)(Bt + (size_t)(n0 + r) * 256) + cb);
    *(ushort8*)((char*)sB + r * 512 + cbs) = vb;
  }
  __syncthreads();

  const int wr = wid >> 1, wc = wid & 1;
  const int lr = lane & 15, kg = lane >> 4;
  f32x4 acc[2][2] = {};
#pragma unroll
  for (int ks = 0; ks < 8; ++ks) {
    int kb = ks * 64 + kg * 16;
    short8 a0, a1, b0, b1;
    { int r = wr * 32 + lr;      a0 = *(const short8*)((const char*)sA + r * 512 + (kb ^ ((r & 7) << 4))); }
    { int r = wr * 32 + 16 + lr; a1 = *(const short8*)((const char*)sA + r * 512 + (kb ^ ((r & 7) << 4))); }
    { int r = wc * 32 + lr;      b0 = *(const short8*)((const char*)sB + r * 512 + (kb ^ ((r & 7) << 4))); }
    { int r = wc * 32 + 16 + lr; b1 = *(const short8*)((const char*)sB + r * 512 + (kb ^ ((r & 7) << 4))); }
    acc[0][0] = __builtin_amdgcn_mfma_f32_16x16x32_bf16(a0, b0, acc[0][0], 0, 0, 0);
    acc[0][1] = __builtin_amdgcn_mfma_f32_16x16x32_bf16(a0, b1, acc[0][1], 0, 0, 0);
    acc[1][0] = __builtin_amdgcn_mfma_f32_16x16x32_bf16(a1, b0, acc[1][0], 0, 0, 0);
    acc[1][1] = __builtin_amdgcn_mfma_f32_16x16x32_bf16(a1, b1, acc[1][1], 0, 0, 0);
  }

#pragma unroll
  for (int mi = 0; mi < 2; ++mi)
#pragma unroll
    for (int ni = 0; ni < 2; ++ni) {
      int col = n0 + wc * 32 + ni * 16 + lr;
#pragma unroll
      for (int r4 = 0; r4 < 4; ++r4) {
        int row = m0 + wr * 32 + mi * 16 + kg * 4 + r4;
        Y[(size_t)row * 1280 + col] = f2bf(acc[mi][ni][r4]);
      }
    }
}

// ---------------------------------------------------------------------------
// Stage one row's seg-CSR (4 segments concatenated, column-sorted) into LDS.
// Returns total nnz. Call with all 256 threads.
__device__ inline int stage_row(const int2* __restrict__ segout,
                                const int* __restrict__ segcnt, int mr, int t,
                                int* sj, float* sv) {
  int4 cn = ((const int4*)segcnt)[mr];
  int c0 = cn.x, p1 = c0 + cn.y, p2 = p1 + cn.z, tot = p2 + cn.w;
  if (t < tot) {
    int s, o;
    if      (t < c0) { s = 0; o = t; }
    else if (t < p1) { s = 1; o = t - c0; }
    else if (t < p2) { s = 2; o = t - p1; }
    else             { s = 3; o = t - p2; }
    int2 e = segout[((size_t)mr * 4 + s) * SEGSLOT + o];
    sj[t] = e.x; sv[t] = __int_as_float(e.y);
  }
  return tot;
}

// ---------------------------------------------------------------------------
// U = Y0 + L @ Y1 (in place into the Y0 column range).
__global__ void spmm_add(const int2* __restrict__ segout, const int* __restrict__ segcnt,
                         unsigned short* __restrict__ Y) {
  int br = blockIdx.y;
  int row = blockIdx.x, t = threadIdx.x;
  __shared__ int   sj[LDSNNZ];
  __shared__ float sv[LDSNNZ];
  int n = stage_row(segout, segcnt, br * NROW + row, t, sj, sv);
  __syncthreads();
  int cs = br ? 768 : 256, cd = br ? 512 : 0;
  float acc = bf2f(Y[(size_t)row * 1280 + cd + t]);
  for (int k = 0; k < n; ++k) acc += sv[k] * bf2f(Y[(size_t)sj[k] * 1280 + cs + t]);
  Y[(size_t)row * 1280 + cd + t] = f2bf(acc);
}

// ---------------------------------------------------------------------------
// Z[row] = alpha_d @ U_d + alpha_s @ U_s + P @ Yh + (all biases)
__global__ void final_z(const int2* __restrict__ segout, const int* __restrict__ segcnt,
                        const float* __restrict__ sdv,
                        const unsigned short* __restrict__ Y,
                        const float* __restrict__ bi, const float* __restrict__ bs,
                        const float* __restrict__ bh, float* __restrict__ Z) {
  int row = blockIdx.x, t = threadIdx.x;
  __shared__ float sa[LDSNNZ];
  __shared__ int   sj[LDSNNZ];
  __shared__ float red[4];
  float acc = bi[t] + bi[256 + t] + bs[t] + bs[256 + t] + bh[t];

  for (int br = 0; br < 2; ++br) {
    int n = stage_row(segout, segcnt, br * NROW + row, t, sj, sa);
    __syncthreads();
    const float* srcv = sdv + (2 * br) * NROW;
    const float* dstv = sdv + (2 * br + 1) * NROW;
    float e = -1e30f;
    if (t < n) {
      float v = srcv[row] + dstv[sj[t]];
      e = v >= 0.f ? v : 0.01f * v;
    }
    float m = e;
    for (int o = 32; o; o >>= 1) m = fmaxf(m, __shfl_xor(m, o));
    if ((t & 63) == 0) red[t >> 6] = m;
    __syncthreads();
    m = fmaxf(fmaxf(red[0], red[1]), fmaxf(red[2], red[3]));
    __syncthreads();
    float p = (t < n) ? expf(e - m) : 0.f;
    float s = p;
    for (int o = 32; o; o >>= 1) s += __shfl_xor(s, o);
    if ((t & 63) == 0) red[t >> 6] = s;
    __syncthreads();
    s = red[0] + red[1] + red[2] + red[3];
    if (t < n) sa[t] = p / s;
    __syncthreads();
    int cd = br ? 512 : 0;
    for (int k = 0; k < n; ++k)
      acc += sa[k] * bf2f(Y[(size_t)sj[k] * 1280 + cd + t]);
    __syncthreads();
  }

  {
    int n = stage_row(segout, segcnt, 2 * NROW + row, t, sj, sa);
    __syncthreads();
    for (int k = 0; k < n; ++k)
      acc += sa[k] * bf2f(Y[(size_t)sj[k] * 1280 + 1024 + t]);
  }
  Z[(size_t)row * 256 + t] = acc;
}

// ---------------------------------------------------------------------------
extern "C" void kernel_launch(void* const* d_in, const int* in_sizes, int n_in,
                              void* d_out, int out_size, void* d_ws, size_t ws_size,
                              hipStream_t stream) {
  const float* x      = (const float*)d_in[0];
  const float* Lup    = (const float*)d_in[1];
  const float* Ld     = (const float*)d_in[2];
  const float* P      = (const float*)d_in[3];
  const float* Wirr_w = (const float*)d_in[4];
  const float* Wirr_b = (const float*)d_in[5];
  const float* Wsol_w = (const float*)d_in[6];
  const float* Wsol_b = (const float*)d_in[7];
  const float* Whar_w = (const float*)d_in[8];
  const float* Whar_b = (const float*)d_in[9];
  const float* att_i  = (const float*)d_in[10];
  const float* att_s  = (const float*)d_in[11];
  float* Z = (float*)d_out;

  char* w = (char*)d_ws;
  auto alloc = [&](size_t bytes) { void* p = (void*)w; w += (bytes + 255) & ~(size_t)255; return p; };

  int2* segout = (int2*)alloc((size_t)3 * NROW * 4 * SEGSLOT * 8);
  int*  segcnt = (int*)alloc((size_t)3 * NROW * 4 * 4);
  float* wfold = (float*)alloc(4 * CH * 4);
  float* bfold = (float*)alloc(4 * 4);
  float* sdv   = (float*)alloc(4 * NROW * 4);
  unsigned short* xbf = (unsigned short*)alloc((size_t)NROW * CH * 2);
  unsigned short* Bbf = (unsigned short*)alloc((size_t)1280 * CH * 2);
  unsigned short* Y   = (unsigned short*)alloc((size_t)NROW * 1280 * 2);

  // mat slot order: 0 = Ld (irr), 1 = Lup (sol), 2 = P
  seg_csr<<<2048, 256, 0, stream>>>(Ld, Lup, P, segout, segcnt);

  fold_att<<<4, 256, 0, stream>>>(Wirr_w, Wirr_b, att_i, Wsol_w, Wsol_b, att_s, wfold, bfold);
  src_dst<<<dim3(NROW / 4, 4), 256, 0, stream>>>(x, wfold, bfold, sdv);

  cvt_all<<<(262144 + 32768 + 32768 + 16384) / 256, 256, 0, stream>>>(x, Wirr_w, Wsol_w, Whar_w, xbf, Bbf);

  gemm_mfma<<<dim3(NROW / 64, 1280 / 64), 256, 0, stream>>>(xbf, Bbf, Y);

  spmm_add<<<dim3(NROW, 2), 256, 0, stream>>>(segout, segcnt, Y);

  final_z<<<NROW, 256, 0, stream>>>(segout, segcnt, sdv, Y, Wirr_b, Wsol_b, Whar_b, Z);
}

// Round 7
// 114.101 us; speedup vs baseline: 1.1552x; 1.1552x over previous
//
#include <hip/hip_runtime.h>

#define NROW 4096
#define CH   256
#define MAXNNZ 128

typedef short  short8  __attribute__((ext_vector_type(8)));
typedef unsigned short ushort8 __attribute__((ext_vector_type(8)));
typedef float  f32x4   __attribute__((ext_vector_type(4)));

__device__ inline unsigned short f2bf(float f) {
  unsigned u = __float_as_uint(f);
  return (unsigned short)((u + 0x7fffu + ((u >> 16) & 1u)) >> 16);
}
__device__ inline float bf2f(unsigned short h) {
  return __uint_as_float((unsigned)h << 16);
}
__device__ inline int mbcnt64(unsigned long long m, int base) {
  int t = __builtin_amdgcn_mbcnt_lo((unsigned)m, (unsigned)base);
  return __builtin_amdgcn_mbcnt_hi((unsigned)(m >> 32), t);
}

// ---------------------------------------------------------------------------
// Build 3 CSRs (Ld, Lup, P). One WAVE per row (block = 4 rows, row-sequential
// dispatch for L3 locality). __launch_bounds__(256,4) raises the VGPR budget
// to ~128 so ALL 16 float4 loads/lane can be hoisted and stay in flight
// (64 data VGPRs): 16KB/wave in flight vs the ~2KB the default-occupancy
// scheduler allowed in prior rounds. Compaction via ballot into per-wave LDS
// (lgkm domain), one coalesced write-out per row.
__global__ __launch_bounds__(256, 4) void build_csr3(
    const float* __restrict__ L0, const float* __restrict__ L1,
    const float* __restrict__ L2, int* __restrict__ idx,
    float* __restrict__ val, int* __restrict__ cnt) {
  __shared__ int   sj[4][MAXNNZ];
  __shared__ float sv[4][MAXNNZ];
  const int mat = blockIdx.y;
  const float* L = (mat == 0) ? L0 : (mat == 1) ? L1 : L2;
  const int wi = threadIdx.x >> 6, lane = threadIdx.x & 63;
  const int row = blockIdx.x * 4 + wi;
  const float4* Lrow = (const float4*)(L + (size_t)row * NROW);

  float4 v0  = Lrow[lane],        v1  = Lrow[64 + lane];
  float4 v2  = Lrow[128 + lane],  v3  = Lrow[192 + lane];
  float4 v4  = Lrow[256 + lane],  v5  = Lrow[320 + lane];
  float4 v6  = Lrow[384 + lane],  v7  = Lrow[448 + lane];
  float4 v8  = Lrow[512 + lane],  v9  = Lrow[576 + lane];
  float4 v10 = Lrow[640 + lane],  v11 = Lrow[704 + lane];
  float4 v12 = Lrow[768 + lane],  v13 = Lrow[832 + lane];
  float4 v14 = Lrow[896 + lane],  v15 = Lrow[960 + lane];
  __builtin_amdgcn_sched_barrier(0);   // all 16 loads issued before compute

  int base = 0;
#define PROCQ(q, cb) {                                                         \
    bool a0 = q.x != 0.f, a1 = q.y != 0.f, a2 = q.z != 0.f, a3 = q.w != 0.f;   \
    unsigned long long b0 = __ballot(a0), b1 = __ballot(a1);                   \
    unsigned long long b2 = __ballot(a2), b3 = __ballot(a3);                   \
    int off = mbcnt64(b3, mbcnt64(b2, mbcnt64(b1, mbcnt64(b0, base))));        \
    if (a0) { if (off < MAXNNZ) { sj[wi][off] = (cb);     sv[wi][off] = q.x; } ++off; } \
    if (a1) { if (off < MAXNNZ) { sj[wi][off] = (cb) + 1; sv[wi][off] = q.y; } ++off; } \
    if (a2) { if (off < MAXNNZ) { sj[wi][off] = (cb) + 2; sv[wi][off] = q.z; } ++off; } \
    if (a3) { if (off < MAXNNZ) { sj[wi][off] = (cb) + 3; sv[wi][off] = q.w; } ++off; } \
    base += __popcll(b0) + __popcll(b1) + __popcll(b2) + __popcll(b3); }
  int cb = lane * 4;
  PROCQ(v0,  cb)        PROCQ(v1,  cb + 256)  PROCQ(v2,  cb + 512)  PROCQ(v3,  cb + 768)
  PROCQ(v4,  cb + 1024) PROCQ(v5,  cb + 1280) PROCQ(v6,  cb + 1536) PROCQ(v7,  cb + 1792)
  PROCQ(v8,  cb + 2048) PROCQ(v9,  cb + 2304) PROCQ(v10, cb + 2560) PROCQ(v11, cb + 2816)
  PROCQ(v12, cb + 3072) PROCQ(v13, cb + 3328) PROCQ(v14, cb + 3584) PROCQ(v15, cb + 3840)
#undef PROCQ

  size_t rbase = ((size_t)mat * NROW + row) * MAXNNZ;
  int2   ji = ((const int2*)sj[wi])[lane];
  float2 vf = ((const float2*)sv[wi])[lane];
  ((int2*)(idx + rbase))[lane] = ji;
  ((float2*)(val + rbase))[lane] = vf;
  if (lane == 0) cnt[mat * NROW + row] = base < MAXNNZ ? base : MAXNNZ;
}

// ---------------------------------------------------------------------------
// One dispatch converting x, Wirr_w, Wsol_w, Whar_w to bf16 (4 f32/thread).
__global__ void cvt_all(const float* __restrict__ x, const float* __restrict__ Wi,
                        const float* __restrict__ Ws, const float* __restrict__ Wh,
                        unsigned short* __restrict__ xbf, unsigned short* __restrict__ Bbf) {
  int i = blockIdx.x * 256 + threadIdx.x;       // float4 index
  const float* src; unsigned short* dst; int o;
  if (i < 262144)        { src = x;  dst = xbf;          o = i; }
  else if (i < 294912)   { src = Wi; dst = Bbf;          o = i - 262144; }
  else if (i < 327680)   { src = Ws; dst = Bbf + 131072; o = i - 294912; }
  else                   { src = Wh; dst = Bbf + 262144; o = i - 327680; }
  float4 v = ((const float4*)src)[o];
  ushort4 u;
  u.x = f2bf(v.x); u.y = f2bf(v.y); u.z = f2bf(v.z); u.w = f2bf(v.w);
  ((ushort4*)dst)[o] = u;
}

// ---------------------------------------------------------------------------
// Y[4096][1280] (bf16) = A[4096][256](bf16) @ Bt[1280][256](bf16)^T
__global__ __launch_bounds__(256, 2) void gemm_mfma(const unsigned short* __restrict__ A,
                                                    const unsigned short* __restrict__ Bt,
                                                    unsigned short* __restrict__ Y) {
  __shared__ unsigned short sA[64 * 256];
  __shared__ unsigned short sB[64 * 256];
  const int m0 = blockIdx.x * 64, n0 = blockIdx.y * 64;
  const int tid = threadIdx.x, wid = tid >> 6, lane = tid & 63;

  for (int c = 0; c < 8; ++c) {
    int chunk = c * 256 + tid;
    int r  = chunk >> 5;
    int cb = (chunk & 31) * 16;
    int cbs = cb ^ ((r & 7) << 4);
    ushort8 va = *(const ushort8*)((const char*)(A  + (size_t)(m0 + r) * 256) + cb);
    *(ushort8*)((char*)sA + r * 512 + cbs) = va;
    ushort8 vb = *(const ushort8*)((const char*)(Bt + (size_t)(n0 + r) * 256) + cb);
    *(ushort8*)((char*)sB + r * 512 + cbs) = vb;
  }
  __syncthreads();

  const int wr = wid >> 1, wc = wid & 1;
  const int lr = lane & 15, kg = lane >> 4;
  f32x4 acc[2][2] = {};
#pragma unroll
  for (int ks = 0; ks < 8; ++ks) {
    int kb = ks * 64 + kg * 16;
    short8 a0, a1, b0, b1;
    { int r = wr * 32 + lr;      a0 = *(const short8*)((const char*)sA + r * 512 + (kb ^ ((r & 7) << 4))); }
    { int r = wr * 32 + 16 + lr; a1 = *(const short8*)((const char*)sA + r * 512 + (kb ^ ((r & 7) << 4))); }
    { int r = wc * 32 + lr;      b0 = *(const short8*)((const char*)sB + r * 512 + (kb ^ ((r & 7) << 4))); }
    { int r = wc * 32 + 16 + lr; b1 = *(const short8*)((const char*)sB + r * 512 + (kb ^ ((r & 7) << 4))); }
    acc[0][0] = __builtin_amdgcn_mfma_f32_16x16x32_bf16(a0, b0, acc[0][0], 0, 0, 0);
    acc[0][1] = __builtin_amdgcn_mfma_f32_16x16x32_bf16(a0, b1, acc[0][1], 0, 0, 0);
    acc[1][0] = __builtin_amdgcn_mfma_f32_16x16x32_bf16(a1, b0, acc[1][0], 0, 0, 0);
    acc[1][1] = __builtin_amdgcn_mfma_f32_16x16x32_bf16(a1, b1, acc[1][1], 0, 0, 0);
  }

#pragma unroll
  for (int mi = 0; mi < 2; ++mi)
#pragma unroll
    for (int ni = 0; ni < 2; ++ni) {
      int col = n0 + wc * 32 + ni * 16 + lr;
#pragma unroll
      for (int r4 = 0; r4 < 4; ++r4) {
        int row = m0 + wr * 32 + mi * 16 + kg * 4 + r4;
        Y[(size_t)row * 1280 + col] = f2bf(acc[mi][ni][r4]);
      }
    }
}

// ---------------------------------------------------------------------------
// sdv[q][row] from Y: cols 0-511 are x_cat_irr, 512-1023 x_cat_sol.
// q=0 irr-src, 1 irr-dst, 2 sol-src, 3 sol-dst. One wave per row.
__global__ __launch_bounds__(256) void sdv_from_y(
    const unsigned short* __restrict__ Y, const float* __restrict__ ai,
    const float* __restrict__ as_, const float* __restrict__ bi,
    const float* __restrict__ bs, float* __restrict__ sdv) {
  __shared__ float satt[2048];
  __shared__ float sbias[4];
  int t = threadIdx.x, wi = t >> 6, lane = t & 63;
  for (int k = t; k < 1024; k += 256) { satt[k] = ai[k]; satt[1024 + k] = as_[k]; }
  {
    const float* av = (wi & 2) ? as_ : ai;
    const float* bv = (wi & 2) ? bs : bi;
    int off = (wi & 1) * 512;
    float b = 0.f;
    for (int k = lane; k < 512; k += 64) b += av[off + k] * bv[k];
    for (int o = 32; o; o >>= 1) b += __shfl_xor(b, o);
    if (lane == 0) sbias[wi] = b;
  }
  __syncthreads();

  int row = blockIdx.x * 4 + wi;
  const ushort8* yr = (const ushort8*)(Y + (size_t)row * 1280);
  ushort8 ya = yr[lane * 2], yb = yr[lane * 2 + 1];
  int c0 = lane * 16;
  int off = (lane < 32) ? 0 : 512;
  float a0 = 0.f, a1 = 0.f;
#pragma unroll
  for (int j = 0; j < 8; ++j) {
    float y = bf2f(ya[j]); int c = c0 + j;
    a0 += satt[off + c] * y; a1 += satt[off + 512 + c] * y;
  }
#pragma unroll
  for (int j = 0; j < 8; ++j) {
    float y = bf2f(yb[j]); int c = c0 + 8 + j;
    a0 += satt[off + c] * y; a1 += satt[off + 512 + c] * y;
  }
  for (int o = 16; o; o >>= 1) { a0 += __shfl_xor(a0, o); a1 += __shfl_xor(a1, o); }
  if (lane == 0)  { sdv[row] = a0 + sbias[0];            sdv[NROW + row] = a1 + sbias[1]; }
  if (lane == 32) { sdv[2 * NROW + row] = a0 + sbias[2]; sdv[3 * NROW + row] = a1 + sbias[3]; }
}

// ---------------------------------------------------------------------------
// U = Y0 + L @ Y1 (in place into the Y0 column range). 4-wave k-split,
// ushort4 (8B/lane) gathers, cross-wave LDS reduce.
__global__ __launch_bounds__(256) void spmm_add(const int* __restrict__ idx,
                                                const float* __restrict__ val,
                                                const int* __restrict__ cnt,
                                                unsigned short* __restrict__ Y) {
  int br = blockIdx.y, row = blockIdx.x;
  int t = threadIdx.x, w = t >> 6, l = t & 63;
  __shared__ int   sj[MAXNNZ];
  __shared__ float sv[MAXNNZ];
  __shared__ float part[4][256];
  size_t rbase = ((size_t)br * NROW + row) * MAXNNZ;
  int n = cnt[br * NROW + row];
  if (t < n) { sj[t] = idx[rbase + t]; sv[t] = val[rbase + t]; }
  __syncthreads();
  int cs = br ? 768 : 256, cd = br ? 512 : 0;
  float4 acc = {0.f, 0.f, 0.f, 0.f};
  for (int k = w; k < n; k += 4) {
    ushort4 y = *(const ushort4*)(Y + (size_t)sj[k] * 1280 + cs + 4 * l);
    float a = sv[k];
    acc.x += a * bf2f(y.x); acc.y += a * bf2f(y.y);
    acc.z += a * bf2f(y.z); acc.w += a * bf2f(y.w);
  }
  ((float4*)part[w])[l] = acc;
  __syncthreads();
  if (t < 64) {
    unsigned short* yp = Y + (size_t)row * 1280 + cd + 4 * t;
    ushort4 yb = *(const ushort4*)yp;
    ushort4 o;
    o.x = f2bf(bf2f(yb.x) + part[0][4 * t]     + part[1][4 * t]     + part[2][4 * t]     + part[3][4 * t]);
    o.y = f2bf(bf2f(yb.y) + part[0][4 * t + 1] + part[1][4 * t + 1] + part[2][4 * t + 1] + part[3][4 * t + 1]);
    o.z = f2bf(bf2f(yb.z) + part[0][4 * t + 2] + part[1][4 * t + 2] + part[2][4 * t + 2] + part[3][4 * t + 2]);
    o.w = f2bf(bf2f(yb.w) + part[0][4 * t + 3] + part[1][4 * t + 3] + part[2][4 * t + 3] + part[3][4 * t + 3]);
    *(ushort4*)yp = o;
  }
}

// ---------------------------------------------------------------------------
// Z[row] = alpha_d @ U_d + alpha_s @ U_s + P @ Yh + (all biases)
__global__ __launch_bounds__(256) void final_z(const int* __restrict__ idx,
                        const float* __restrict__ val, const int* __restrict__ cnt,
                        const float* __restrict__ sdv,
                        const unsigned short* __restrict__ Y,
                        const float* __restrict__ bi, const float* __restrict__ bs,
                        const float* __restrict__ bh, float* __restrict__ Z) {
  int row = blockIdx.x, t = threadIdx.x, w = t >> 6, l = t & 63;
  __shared__ float sa[MAXNNZ];
  __shared__ int   sj[MAXNNZ];
  __shared__ float red[4];
  __shared__ float part[4][256];
  float4 acc = {0.f, 0.f, 0.f, 0.f};

  for (int br = 0; br < 2; ++br) {
    size_t rbase = ((size_t)br * NROW + row) * MAXNNZ;
    int n = cnt[br * NROW + row];
    const float* srcv = sdv + (2 * br) * NROW;
    const float* dstv = sdv + (2 * br + 1) * NROW;
    float e = -1e30f;
    if (t < n) {
      int j = idx[rbase + t];
      sj[t] = j;
      float v = srcv[row] + dstv[j];
      e = v >= 0.f ? v : 0.01f * v;
    }
    float m = e;
    for (int o = 32; o; o >>= 1) m = fmaxf(m, __shfl_xor(m, o));
    if ((t & 63) == 0) red[t >> 6] = m;
    __syncthreads();
    m = fmaxf(fmaxf(red[0], red[1]), fmaxf(red[2], red[3]));
    __syncthreads();
    float p = (t < n) ? expf(e - m) : 0.f;
    float s = p;
    for (int o = 32; o; o >>= 1) s += __shfl_xor(s, o);
    if ((t & 63) == 0) red[t >> 6] = s;
    __syncthreads();
    s = red[0] + red[1] + red[2] + red[3];
    if (t < n) sa[t] = p / s;
    __syncthreads();
    int cd = br ? 512 : 0;
    for (int k = w; k < n; k += 4) {
      ushort4 y = *(const ushort4*)(Y + (size_t)sj[k] * 1280 + cd + 4 * l);
      float a = sa[k];
      acc.x += a * bf2f(y.x); acc.y += a * bf2f(y.y);
      acc.z += a * bf2f(y.z); acc.w += a * bf2f(y.w);
    }
    __syncthreads();   // before next branch rewrites sa/sj/red
  }

  {
    size_t rbase = ((size_t)2 * NROW + row) * MAXNNZ;
    int n = cnt[2 * NROW + row];
    if (t < n) { sj[t] = idx[rbase + t]; sa[t] = val[rbase + t]; }
    __syncthreads();
    for (int k = w; k < n; k += 4) {
      ushort4 y = *(const ushort4*)(Y + (size_t)sj[k] * 1280 + 1024 + 4 * l);
      float a = sa[k];
      acc.x += a * bf2f(y.x); acc.y += a * bf2f(y.y);
      acc.z += a * bf2f(y.z); acc.w += a * bf2f(y.w);
    }
  }
  ((float4*)part[w])[l] = acc;
  __syncthreads();
  if (t < 64) {
    float4 r;
    int c = 4 * t;
    r.x = part[0][c]     + part[1][c]     + part[2][c]     + part[3][c]     + bi[c]     + bi[256 + c]     + bs[c]     + bs[256 + c]     + bh[c];
    r.y = part[0][c + 1] + part[1][c + 1] + part[2][c + 1] + part[3][c + 1] + bi[c + 1] + bi[257 + c]     + bs[c + 1] + bs[257 + c]     + bh[c + 1];
    r.z = part[0][c + 2] + part[1][c + 2] + part[2][c + 2] + part[3][c + 2] + bi[c + 2] + bi[258 + c]     + bs[c + 2] + bs[258 + c]     + bh[c + 2];
    r.w = part[0][c + 3] + part[1][c + 3] + part[2][c + 3] + part[3][c + 3] + bi[c + 3] + bi[259 + c]     + bs[c + 3] + bs[259 + c]     + bh[c + 3];
    *(float4*)(Z + (size_t)row * 256 + c) = r;
  }
}

// ---------------------------------------------------------------------------
extern "C" void kernel_launch(void* const* d_in, const int* in_sizes, int n_in,
                              void* d_out, int out_size, void* d_ws, size_t ws_size,
                              hipStream_t stream) {
  const float* x      = (const float*)d_in[0];
  const float* Lup    = (const float*)d_in[1];
  const float* Ld     = (const float*)d_in[2];
  const float* P      = (const float*)d_in[3];
  const float* Wirr_w = (const float*)d_in[4];
  const float* Wirr_b = (const float*)d_in[5];
  const float* Wsol_w = (const float*)d_in[6];
  const float* Wsol_b = (const float*)d_in[7];
  const float* Whar_w = (const float*)d_in[8];
  const float* Whar_b = (const float*)d_in[9];
  const float* att_i  = (const float*)d_in[10];
  const float* att_s  = (const float*)d_in[11];
  float* Z = (float*)d_out;

  char* w = (char*)d_ws;
  auto alloc = [&](size_t bytes) { void* p = (void*)w; w += (bytes + 255) & ~(size_t)255; return p; };

  int*   idx  = (int*)alloc((size_t)3 * NROW * MAXNNZ * 4);
  float* val  = (float*)alloc((size_t)3 * NROW * MAXNNZ * 4);
  int*   cnt  = (int*)alloc((size_t)3 * NROW * 4);
  float* sdv  = (float*)alloc(4 * NROW * 4);
  unsigned short* xbf = (unsigned short*)alloc((size_t)NROW * CH * 2);
  unsigned short* Bbf = (unsigned short*)alloc((size_t)1280 * CH * 2);
  unsigned short* Y   = (unsigned short*)alloc((size_t)NROW * 1280 * 2);

  // mat slot order: 0 = Ld (irr), 1 = Lup (sol), 2 = P
  build_csr3<<<dim3(NROW / 4, 3), 256, 0, stream>>>(Ld, Lup, P, idx, val, cnt);

  cvt_all<<<(262144 + 32768 + 32768 + 16384) / 256, 256, 0, stream>>>(x, Wirr_w, Wsol_w, Whar_w, xbf, Bbf);

  gemm_mfma<<<dim3(NROW / 64, 1280 / 64), 256, 0, stream>>>(xbf, Bbf, Y);

  sdv_from_y<<<NROW / 4, 256, 0, stream>>>(Y, att_i, att_s, Wirr_b, Wsol_b, sdv);

  spmm_add<<<dim3(NROW, 2), 256, 0, stream>>>(idx, val, cnt, Y);

  final_z<<<NROW, 256, 0, stream>>>(idx, val, cnt, sdv, Y, Wirr_b, Wsol_b, Whar_b, Z);
}